// Round 9
// baseline (186.941 us; speedup 1.0000x reference)
//
#include <hip/hip_runtime.h>

#define NCLS 88
#define DHW (96 * 96 * 96)            // 884736
#define TPB 512                       // 8 waves, 8-way class split
#define WAVES 8
#define CPW 11                        // classes per wave
#define VPJ 256                       // voxels per block per j-iter (64 lanes x 4)
#define NJ 2
#define VOX_PER_BLOCK (VPJ * NJ)      // 512
#define BLOCKS_PER_B (DHW / VOX_PER_BLOCK)   // 1728, exact
#define SLOTS 32
#define SMOOTH 1e-5f
#define WS_PER_SLOT 529
// ws layout per slot: [0..176) inter[b*88+c] | [176..352) pred_o | [352..528) cnt | [528] ce

typedef float f2 __attribute__((ext_vector_type(2)));

__device__ __forceinline__ float wave_reduce_sum(float v) {
#pragma unroll
    for (int i = 1; i < 64; i <<= 1)
        v += __shfl_xor(v, i, 64);
    return v;
}

// NOTE: no min-waves arg — __launch_bounds__(TPB,N) forced 64-VGPR + ~1.5 GB
// spill traffic in R4/R6. Plain bound: ~85 VGPR, no scratch.
__global__ __launch_bounds__(TPB)
void seg_loss_main(const float* __restrict__ pred, const int* __restrict__ tgt,
                   float* __restrict__ ws) {
    __shared__ float s_inter[NCLS];
    __shared__ float s_pred[NCLS];
    __shared__ float s_cnt[NCLS];
    __shared__ float s_ce;
    __shared__ float2 s_ex[NJ][WAVES][4][64];  // [j][wave][vox][lane] = {s1_part, et_part}

    const int tid  = threadIdx.x;
    const int lane = tid & 63;
    const int wave = tid >> 6;                 // 0..7
    const int b    = blockIdx.x / BLOCKS_PER_B;
    const int base = (blockIdx.x % BLOCKS_PER_B) * VOX_PER_BLOCK;
    const int cls0 = wave * CPW;
    const float* pb = pred + (size_t)b * NCLS * DHW + (size_t)cls0 * DHW;
    const int*   tb = tgt  + (size_t)b * DHW;

    if (tid < NCLS) { s_inter[tid] = 0.f; s_pred[tid] = 0.f; s_cnt[tid] = 0.f; }
    if (tid == 0) s_ce = 0.f;
    __syncthreads();

    float acc[CPW];                    // my 11 classes' sum of p^2 (fp32)
#pragma unroll
    for (int i = 0; i < CPW; ++i) acc[i] = 0.f;
    float ce_acc = 0.f;

    for (int j = 0; j < NJ; ++j) {
        const int vox = base + j * VPJ + lane * 4;
        const int4 t4 = *(const int4*)(tb + vox);
        const int tv[4] = { t4.x, t4.y, t4.z, t4.w };
        bool  val[4]; int tc[4]; float vf[4];
#pragma unroll
        for (int v = 0; v < 4; ++v) {
            val[v] = (tv[v] != -1);
            tc[v]  = val[v] ? tv[v] : 0;
            vf[v]  = val[v] ? 1.f : 0.f;
        }
        const float* p = pb + vox;

        // ---- pass A: 11 classes x float4 (4 voxels/lane), fp8-packed exps ----
        float sA[4] = {0,0,0,0}, sB[4] = {0,0,0,0};
        float eta[4] = {0,0,0,0}, etb[4] = {0,0,0,0};
        int ef[CPW];
#pragma unroll
        for (int c = 0; c < CPW; ++c) {
            const float4 x = *(const float4*)(p + (size_t)c * DHW);
            const float e0 = __expf(x.x * vf[0]);
            const float e1 = __expf(x.y * vf[1]);
            const float e2 = __expf(x.z * vf[2]);
            const float e3 = __expf(x.w * vf[3]);
            const int cc = cls0 + c;
            if (c & 1) {
                sB[0] += e0; sB[1] += e1; sB[2] += e2; sB[3] += e3;
                etb[0] = (cc == tc[0]) ? e0 : etb[0];
                etb[1] = (cc == tc[1]) ? e1 : etb[1];
                etb[2] = (cc == tc[2]) ? e2 : etb[2];
                etb[3] = (cc == tc[3]) ? e3 : etb[3];
            } else {
                sA[0] += e0; sA[1] += e1; sA[2] += e2; sA[3] += e3;
                eta[0] = (cc == tc[0]) ? e0 : eta[0];
                eta[1] = (cc == tc[1]) ? e1 : eta[1];
                eta[2] = (cc == tc[2]) ? e2 : eta[2];
                eta[3] = (cc == tc[3]) ? e3 : eta[3];
            }
            const int lo = __builtin_amdgcn_cvt_pk_fp8_f32(e0, e1, 0, false);
            ef[c] = __builtin_amdgcn_cvt_pk_fp8_f32(e2, e3, lo, true);
        }

        // ---- cross-wave exchange: one barrier per j (j-parity buffers) ----
#pragma unroll
        for (int v = 0; v < 4; ++v)
            s_ex[j][wave][v][lane] = make_float2(sA[v] + sB[v], eta[v] + etb[v]);
        __syncthreads();

        float inv[4], pt[4];
#pragma unroll
        for (int v = 0; v < 4; ++v) {
            float s1 = 0.f, et = 0.f;
#pragma unroll
            for (int w = 0; w < WAVES; ++w) {
                const float2 q = s_ex[j][w][v][lane];
                s1 += q.x; et += q.y;
            }
            inv[v] = 1.f / s1;
            pt[v]  = et * inv[v];
        }

        // ---- CE + inter/cnt, owner wave only ----
#pragma unroll
        for (int v = 0; v < 4; ++v) {
            const bool own = (tc[v] >= cls0) && (tc[v] < cls0 + CPW);
            if (val[v] && own) {
                ce_acc -= __logf(pt[v]);
                atomicAdd(&s_inter[tc[v]], pt[v]);
                atomicAdd(&s_cnt[tc[v]], 1.f);
            }
        }

        // ---- pass B: p^2 per class over 4 voxels, fp32 accumulators ----
#pragma unroll
        for (int c = 0; c < CPW; ++c) {
            const f2 lo = __builtin_amdgcn_cvt_pk_f32_fp8(ef[c], false);
            const f2 hi = __builtin_amdgcn_cvt_pk_f32_fp8(ef[c], true);
            const float a0 = lo.x * inv[0], a1 = lo.y * inv[1];
            const float a2 = hi.x * inv[2], a3 = hi.y * inv[3];
            acc[c] += (a0 * a0 + a1 * a1) + (a2 * a2 + a3 * a3);
        }
    }

    // ---- one wave-reduce per class per thread lifetime ----
#pragma unroll
    for (int c = 0; c < CPW; ++c) {
        const float r = wave_reduce_sum(acc[c]);
        if (lane == 0) s_pred[cls0 + c] += r;   // sole owner wave -> plain add
    }
    ce_acc = wave_reduce_sum(ce_acc);
    if (lane == 0) atomicAdd(&s_ce, ce_acc);

    __syncthreads();

    // ---- block partials -> striped global slots ----
    float* wsl = ws + (size_t)(blockIdx.x & (SLOTS - 1)) * WS_PER_SLOT;
    if (tid < NCLS) {
        atomicAdd(&wsl[0 * 176 + b * NCLS + tid], s_inter[tid]);
        atomicAdd(&wsl[1 * 176 + b * NCLS + tid], s_pred[tid]);
        atomicAdd(&wsl[2 * 176 + b * NCLS + tid], s_cnt[tid]);
    }
    if (tid == 0) atomicAdd(&wsl[528], s_ce);
}

__global__ __launch_bounds__(256)
void seg_loss_final(const float* __restrict__ ws, float* __restrict__ out) {
    const int tid = threadIdx.x;
    float dice = 0.f, cnt = 0.f;
    if (tid < 2 * NCLS) {
        float I = 0.f, P = 0.f, G = 0.f;
        for (int s = 0; s < SLOTS; ++s) {
            const float* w = ws + (size_t)s * WS_PER_SLOT;
            I += w[tid]; P += w[176 + tid]; G += w[352 + tid];
        }
        dice = 1.f - (2.f * I + SMOOTH) / (G + P + SMOOTH);
        cnt  = G;
    }
    float ce_s = 0.f;
    if (tid < SLOTS) ce_s = ws[(size_t)tid * WS_PER_SLOT + 528];

    dice = wave_reduce_sum(dice);
    cnt  = wave_reduce_sum(cnt);
    ce_s = wave_reduce_sum(ce_s);

    __shared__ float sd[4], sc2[4], se[4];
    const int w = tid >> 6, l = tid & 63;
    if (l == 0) { sd[w] = dice; sc2[w] = cnt; se[w] = ce_s; }
    __syncthreads();
    if (tid == 0) {
        const float D  = sd[0] + sd[1] + sd[2] + sd[3];
        const float Cn = sc2[0] + sc2[1] + sc2[2] + sc2[3];
        const float CE = (se[0] + se[1] + se[2] + se[3]) / fmaxf(Cn, 1.0f);
        out[0] = 0.4f * CE + 0.6f * (D / 176.f);
    }
}

extern "C" void kernel_launch(void* const* d_in, const int* in_sizes, int n_in,
                              void* d_out, int out_size, void* d_ws, size_t ws_size,
                              hipStream_t stream) {
    const float* pred = (const float*)d_in[0];
    const int*   tgt  = (const int*)d_in[1];
    float* ws = (float*)d_ws;

    (void)hipMemsetAsync(d_ws, 0, SLOTS * WS_PER_SLOT * sizeof(float), stream);
    seg_loss_main<<<2 * BLOCKS_PER_B, TPB, 0, stream>>>(pred, tgt, ws);
    seg_loss_final<<<1, 256, 0, stream>>>(ws, (float*)d_out);
}